// Round 6
// baseline (6369.453 us; speedup 1.0000x reference)
//
#include <hip/hip_runtime.h>
#include <math.h>

// DreamBeliefTracker — round 10: 3-launch hybrid + by-paired GEMM (128x128).
//  * Round-9 (passed, 6307 µs) measured: work ~65 µs/step dominated by LDS
//    staging traffic (~270 MB/step), of which ~100 MB is A-panel re-streaming
//    (N_tile=64 vs N=3072). k_bfused (12-block latency-bound prologue) was the
//    longest dispatch at 88 µs/iteration.
//  * Round-10: dev_mgemm2 = by-paired tile 128x128 — A staged once per K-iter
//    for 2 W panels (ring-2 LDS 64 KB, counted vmcnt(8), trailing barrier for
//    buffer-reuse safety). Tasks halve; staging -90 MB/step. k_bfused unrolled.
//    Per-element K-order and 3-MFMA plane sequence unchanged (bit-exact).
//    Flag/spin protocol identical to round 9 (targets 96/48/32 per bx).

typedef _Float16 f16;
typedef _Float16 f16x8 __attribute__((ext_vector_type(8)));
typedef float f32x4 __attribute__((ext_vector_type(4)));

constexpr int kB = 256, kN1 = 1024, kG3N = 3072, kActD = 6, kT = 64;
constexpr float kLoScale = 4096.f;
constexpr float kLoInv = 1.f / 4096.f;

// ---- coherent (cross-XCD via MALL) accessors for WITHIN-launch data ----
__device__ __forceinline__ float lda_sc(const float* p) {
  return __hip_atomic_load(p, __ATOMIC_RELAXED, __HIP_MEMORY_SCOPE_AGENT);
}
__device__ __forceinline__ void stg_sc(float* p, float v) {
  __hip_atomic_store(p, v, __ATOMIC_RELAXED, __HIP_MEMORY_SCOPE_AGENT);
}
__device__ __forceinline__ int aadd(int* p, int v) {
  return __hip_atomic_fetch_add(p, v, __ATOMIC_RELAXED, __HIP_MEMORY_SCOPE_AGENT);
}
__device__ __forceinline__ int ald(int* p) {
  return __hip_atomic_load(p, __ATOMIC_RELAXED, __HIP_MEMORY_SCOPE_AGENT);
}

__device__ __forceinline__ void wr_planes(f16* hi, f16* lo, size_t i, float x) {
  f16 h = (f16)x;
  hi[i] = h;
  lo[i] = (f16)((x - (float)h) * kLoScale);
}

// plain cacheable DMA (operands cross launch boundaries -> L2-coherent)
__device__ __forceinline__ void glds16(const f16* g, f16* l) {
  __builtin_amdgcn_global_load_lds(
      (const __attribute__((address_space(1))) unsigned int*)g,
      (__attribute__((address_space(3))) unsigned int*)l, 16, 0, 0);
}

// ---------------------------------------------------------- LDS structures
struct GemmLDS  { f16 As[3][2][8][64][8]; f16 Ws[3][2][4][64][8]; };  // 72 KB (prologue)
struct Gemm2LDS { f16 As[2][2][8][64][8]; f16 Ws[2][2][8][64][8]; };  // 64 KB (scan)
struct GruLDS  { float sh[kG3N]; float red[8]; };
struct SmpLDS  { float skl[32]; int sidx[32]; };
union GGLDS { Gemm2LDS g; GruLDS r; };
union ESLDS { Gemm2LDS g; SmpLDS s; };

// --------------------------------------------- by-paired MFMA GEMM (scan) ---
// 256 threads (4 waves, 2m x 2n-half), tile 128x128, BK=32, ring-2 LDS,
// counted vmcnt(8) 1-deep prefetch + trailing barrier (buffer-reuse safety).
// Per-output-element math identical to round-9 dev_mgemm (bit-exact).
__device__ void dev_mgemm2(Gemm2LDS& L, const f16* A1h, const f16* A1l,
                           const f16* A2h, const f16* A2l,
                           const f16* Wph, const f16* Wpl, float* outF,
                           int cols1, int K, int Nout, int k0, int klen,
                           int bx, int byp, int pstride, int pidx) {
  const int m0 = bx * 128, n0 = byp * 128;
  const int tid = threadIdx.x, wave = tid >> 6, lane = tid & 63;
  const int rlo = lane & 15, khi = (lane >> 4) * 8;
  const int wmf = (wave & 1) * 4, wnf = (wave >> 1) * 4;

  f32x4 acc1[4][4], acc2[4][4];
#pragma unroll
  for (int i = 0; i < 4; ++i)
#pragma unroll
    for (int j = 0; j < 4; ++j)
#pragma unroll
      for (int r = 0; r < 4; ++r) { acc1[i][j][r] = 0.f; acc2[i][j][r] = 0.f; }

  auto issueTile = [&](int it, int buf) {   // 8 DMAs per wave
    const int kg = k0 + it * 32;
    const f16 *h, *l; int rs, cb;
    if (kg < cols1) { h = A1h; l = A1l; rs = cols1; cb = kg; }
    else { h = A2h; l = A2l; rs = K - cols1; cb = kg - cols1; }
#pragma unroll
    for (int i = 0; i < 2; ++i) {
      const int mf = wave * 2 + i;
      const size_t go = (size_t)(m0 + mf * 16 + rlo) * rs + cb + khi;
      glds16(h + go, &L.As[buf][0][mf][0][0]);
      glds16(l + go, &L.As[buf][1][mf][0][0]);
    }
#pragma unroll
    for (int i = 0; i < 2; ++i) {
      const int p = wave * 2 + i;
      const size_t wo = (size_t)(n0 + p * 16 + rlo) * K + kg + khi;
      glds16(Wph + wo, &L.Ws[buf][0][p][0][0]);
      glds16(Wpl + wo, &L.Ws[buf][1][p][0][0]);
    }
  };

  const int niter = klen >> 5;
  issueTile(0, 0);
#pragma unroll 1
  for (int it = 0; it < niter; ++it) {
    const int buf = it & 1;
    if (it + 1 < niter) {
      issueTile(it + 1, buf ^ 1);
      asm volatile("s_waitcnt vmcnt(8)" ::: "memory");   // iter-it DMAs done
    } else {
      asm volatile("s_waitcnt vmcnt(0)" ::: "memory");
    }
    __builtin_amdgcn_s_barrier();           // all waves' DMAs for `it` landed
    asm volatile("" ::: "memory");
    f16x8 Af[4][2], Wf[4][2];
#pragma unroll
    for (int mf = 0; mf < 4; ++mf) {
      Af[mf][0] = *(const f16x8*)&L.As[buf][0][wmf + mf][lane][0];
      Af[mf][1] = *(const f16x8*)&L.As[buf][1][wmf + mf][lane][0];
    }
#pragma unroll
    for (int nf = 0; nf < 4; ++nf) {
      Wf[nf][0] = *(const f16x8*)&L.Ws[buf][0][wnf + nf][lane][0];
      Wf[nf][1] = *(const f16x8*)&L.Ws[buf][1][wnf + nf][lane][0];
    }
#pragma unroll
    for (int mf = 0; mf < 4; ++mf)
#pragma unroll
      for (int nf = 0; nf < 4; ++nf) {
        acc1[mf][nf] = __builtin_amdgcn_mfma_f32_16x16x32_f16(Af[mf][0], Wf[nf][0], acc1[mf][nf], 0, 0, 0);
        acc2[mf][nf] = __builtin_amdgcn_mfma_f32_16x16x32_f16(Af[mf][0], Wf[nf][1], acc2[mf][nf], 0, 0, 0);
        acc2[mf][nf] = __builtin_amdgcn_mfma_f32_16x16x32_f16(Af[mf][1], Wf[nf][0], acc2[mf][nf], 0, 0, 0);
      }
    __builtin_amdgcn_s_barrier();           // all waves done with buf before overwrite
  }
  __syncthreads();
  const int orow = m0 + (wave & 1) * 64, ocol = n0 + (wave >> 1) * 64;
#pragma unroll
  for (int mf = 0; mf < 4; ++mf)
#pragma unroll
    for (int nf = 0; nf < 4; ++nf)
#pragma unroll
      for (int r = 0; r < 4; ++r) {
        const int row = orow + mf * 16 + (lane >> 4) * 4 + r;
        const int col = ocol + nf * 16 + rlo;
        const int o = row * Nout + col;
        float* dst = outF + ((size_t)(o >> 4) * pstride + pidx) * 16 + (o & 15);
        stg_sc(dst, acc1[mf][nf][r] + acc2[mf][nf][r] * kLoInv);
      }
}

// ----------------------------- prologue GEMM (round-8 ring-3, unchanged) ----
__device__ void dev_mgemm(GemmLDS& L, const f16* A1h, const f16* A1l,
                          const f16* A2h, const f16* A2l,
                          const f16* Wph, const f16* Wpl, float* outF,
                          int cols1, int K, int Nout, int k0, int klen,
                          int bx, int by, int pstride, int pidx) {
  const int m0 = bx * 128, n0 = by * 64;
  const int tid = threadIdx.x, wave = tid >> 6, lane = tid & 63;
  const int rlo = lane & 15, khi = (lane >> 4) * 8;
  const int wmf = (wave & 1) * 4, wnf = (wave >> 1) * 2;

  f32x4 acc1[4][2], acc2[4][2];
#pragma unroll
  for (int i = 0; i < 4; ++i)
#pragma unroll
    for (int j = 0; j < 2; ++j)
#pragma unroll
      for (int r = 0; r < 4; ++r) { acc1[i][j][r] = 0.f; acc2[i][j][r] = 0.f; }

  auto issueTile = [&](int it, int buf) {
    const int kg = k0 + it * 32;
    const f16 *h, *l; int rs, cb;
    if (kg < cols1) { h = A1h; l = A1l; rs = cols1; cb = kg; }
    else { h = A2h; l = A2l; rs = K - cols1; cb = kg - cols1; }
#pragma unroll
    for (int i = 0; i < 2; ++i) {
      const int mf = wave * 2 + i;
      const size_t go = (size_t)(m0 + mf * 16 + rlo) * rs + cb + khi;
      glds16(h + go, &L.As[buf][0][mf][0][0]);
      glds16(l + go, &L.As[buf][1][mf][0][0]);
    }
    const size_t wo = (size_t)(n0 + wave * 16 + rlo) * K + kg + khi;
    glds16(Wph + wo, &L.Ws[buf][0][wave][0][0]);
    glds16(Wpl + wo, &L.Ws[buf][1][wave][0][0]);
  };

  const int niter = klen >> 5;
  issueTile(0, 0);
  if (niter > 1) issueTile(1, 1);
#pragma unroll 1
  for (int it = 0; it < niter; ++it) {
    const int buf = it % 3;
    if (it + 1 < niter) {
      asm volatile("s_waitcnt vmcnt(6)" ::: "memory");
    } else {
      asm volatile("s_waitcnt vmcnt(0)" ::: "memory");
    }
    __builtin_amdgcn_s_barrier();
    asm volatile("" ::: "memory");
    if (it + 2 < niter) issueTile(it + 2, (it + 2) % 3);
    f16x8 Af[4][2], Wf[2][2];
#pragma unroll
    for (int mf = 0; mf < 4; ++mf) {
      Af[mf][0] = *(const f16x8*)&L.As[buf][0][wmf + mf][lane][0];
      Af[mf][1] = *(const f16x8*)&L.As[buf][1][wmf + mf][lane][0];
    }
#pragma unroll
    for (int nf = 0; nf < 2; ++nf) {
      Wf[nf][0] = *(const f16x8*)&L.Ws[buf][0][wnf + nf][lane][0];
      Wf[nf][1] = *(const f16x8*)&L.Ws[buf][1][wnf + nf][lane][0];
    }
#pragma unroll
    for (int mf = 0; mf < 4; ++mf)
#pragma unroll
      for (int nf = 0; nf < 2; ++nf) {
        acc1[mf][nf] = __builtin_amdgcn_mfma_f32_16x16x32_f16(Af[mf][0], Wf[nf][0], acc1[mf][nf], 0, 0, 0);
        acc2[mf][nf] = __builtin_amdgcn_mfma_f32_16x16x32_f16(Af[mf][0], Wf[nf][1], acc2[mf][nf], 0, 0, 0);
        acc2[mf][nf] = __builtin_amdgcn_mfma_f32_16x16x32_f16(Af[mf][1], Wf[nf][0], acc2[mf][nf], 0, 0, 0);
      }
  }
  __syncthreads();
  const int orow = m0 + (wave & 1) * 64, ocol = n0 + (wave >> 1) * 32;
#pragma unroll
  for (int mf = 0; mf < 4; ++mf)
#pragma unroll
    for (int nf = 0; nf < 2; ++nf)
#pragma unroll
      for (int r = 0; r < 4; ++r) {
        const int row = orow + mf * 16 + (lane >> 4) * 4 + r;
        const int col = ocol + nf * 16 + rlo;
        const int o = row * Nout + col;
        float* dst = outF + ((size_t)(o >> 4) * pstride + pidx) * 16 + (o & 15);
        stg_sc(dst, acc1[mf][nf][r] + acc2[mf][nf][r] * kLoInv);
      }
}

// flag helpers: producer drains sc stores then bumps; consumer spins.
__device__ __forceinline__ void flag_bump(int* ctr) {
  asm volatile("s_waitcnt vmcnt(0)" ::: "memory");
  __syncthreads();
  if (threadIdx.x == 0) aadd(ctr, 1);
}
__device__ __forceinline__ void spin_ge(int* p, int tgt) {
  if (threadIdx.x == 0) {
    int guard = 0;
    while (ald(p) < tgt) {
      __builtin_amdgcn_s_sleep(4);
      if (++guard > (1 << 17)) break;
    }
  }
  __syncthreads();
}

// bx twins (2m,2m+1 sharing W panels) -> same XCD class (perf heuristic)
__device__ __forceinline__ int permW(int B2, int pairsPerCls) {
  const int cls = B2 & 7, k = B2 >> 3;
  return ((cls * pairsPerCls + (k >> 1)) << 1) | (k & 1);
}

// =================== launch A: gates GEMM + LayerNorm/GRU ===================
struct GGArgs {
  const f16 *h1h, *h1l, *bh_r, *bl_r;
  const f16 *WfTh, *WfTl, *WgBh, *WgBl;
  float* Pg;
  const float *bfused, *lns, *lnb, *obs;
  float* bbuf;
  f16 *bh_w, *bl_w, *onh, *onl;
  int* ctr;
  int t;
};

__global__ __launch_bounds__(256, 2) void k_gates_gru(GGArgs a) {
  __shared__ GGLDS L;
  const int t = a.t;
  if (blockIdx.x < 192) {   // 192 tasks: j(4) x byp(24) x bx(2)
    const int task = permW(blockIdx.x, 12);
    const int j = task / 48, r = task % 48, bx = r & 1, byp = r >> 1;
    const bool top = (j < 2);
    dev_mgemm2(L.g, top ? a.h1h : a.bh_r, top ? a.h1l : a.bl_r, nullptr, nullptr,
               top ? a.WfTh : a.WgBh, top ? a.WfTl : a.WgBl,
               a.Pg, 1024, 1024, kG3N, (j & 1) * 512, 512, bx, byp, 4, j);
    flag_bump(a.ctr + bx * 16);
  }
  const int b = blockIdx.x;
  if (b >= kB) return;
  spin_ge(a.ctr + (b >> 7) * 16, (t + 1) * 96);

  // ---- LayerNorm + GRU (sums 4 gate partials; bit-exact) ----
  GruLDS& G = L.r;
  const int tid = threadIdx.x;
  float v[12];
  float sum = 0.f, sq = 0.f;
#pragma unroll
  for (int i = 0; i < 12; ++i) {
    const int j = tid + i * 256;
    const size_t o = (size_t)b * kG3N + j;
    const float* base = a.Pg + ((o >> 4) * 4) * 16 + (o & 15);
    const float q0 = lda_sc(base),      q1 = lda_sc(base + 16);
    const float q2 = lda_sc(base + 32), q3 = lda_sc(base + 48);
    const float s = (((q0 + q1) + q2) + q3) + a.bfused[j];
    v[i] = s; sum += s; sq += s * s;
  }
  if (t < kT - 1) {
#pragma unroll
    for (int i = 0; i < 4; ++i) {
      const int j = tid + i * 256;
      wr_planes(a.onh, a.onl, (size_t)b * kN1 + j,
                a.obs[(size_t)(t + 1) * kB * kN1 + (size_t)b * kN1 + j]);
    }
  }
  for (int m = 1; m <= 32; m <<= 1) { sum += __shfl_xor(sum, m); sq += __shfl_xor(sq, m); }
  if ((tid & 63) == 0) { G.red[(tid >> 6) * 2] = sum; G.red[(tid >> 6) * 2 + 1] = sq; }
  __syncthreads();
  float ts = 0.f, tq = 0.f;
  for (int w = 0; w < 4; ++w) { ts += G.red[w * 2]; tq += G.red[w * 2 + 1]; }
  const float mu   = ts * (1.f / kG3N);
  const float var  = tq * (1.f / kG3N) - mu * mu;
  const float rinv = 1.f / sqrtf(var + 1e-3f);
#pragma unroll
  for (int i = 0; i < 12; ++i) {
    const int j = tid + i * 256;
    G.sh[j] = (v[i] - mu) * rinv * a.lns[j] + a.lnb[j];
  }
  __syncthreads();
#pragma unroll
  for (int i = 0; i < 4; ++i) {
    const int j = tid + i * 256;
    const float r = G.sh[j], c = G.sh[kN1 + j], u = G.sh[2 * kN1 + j];
    const float reset = 1.f / (1.f + expf(-r));
    const float cand  = tanhf(reset * c);
    const float upd   = 1.f / (1.f + expf(-(u - 1.f)));   // UPDATE_BIAS = -1
    const size_t o = (size_t)b * kN1 + j;
    const float bn = upd * cand + (1.f - upd) * a.bbuf[o];
    a.bbuf[o] = bn;
    wr_planes(a.bh_w, a.bl_w, o, bn);
  }
}

// ====================== launch B: D GEMM + combine/silu =====================
struct DCArgs {
  const f16 *bh, *bl, *oth, *otl;
  const f16 *Wp1Th, *Wp1Tl, *Wo1Th, *Wo1Tl;
  float* PD;
  const float *bp1, *bo1;
  f16 *hph, *hpl, *hoh, *hol;
  int* ctr;
  int t;
};

__global__ __launch_bounds__(256, 2) void k_d_comb(DCArgs a) {
  __shared__ Gemm2LDS L;
  const int t = a.t;
  if (blockIdx.x < 96) {    // 96 tasks: j(6) x byp(8) x bx(2)
    const int task = permW(blockIdx.x, 6);
    const int j = task >> 4, r = task & 15, bx = r & 1, byp = r >> 1;
    const f16 *Ah, *Al, *A2h = nullptr, *A2l = nullptr, *Wh, *Wl;
    int K, k0;
    if (j < 2) { Ah = a.bh; Al = a.bl; Wh = a.Wp1Th; Wl = a.Wp1Tl; K = 1024; k0 = j * 512; }
    else { Ah = a.oth; Al = a.otl; A2h = a.bh; A2l = a.bl; Wh = a.Wo1Th; Wl = a.Wo1Tl; K = 2048; k0 = (j - 2) * 512; }
    dev_mgemm2(L, Ah, Al, A2h, A2l, Wh, Wl, a.PD, 1024, K, kN1, k0, 512, bx, byp, 6, j);
    flag_bump(a.ctr + bx * 16);
  }
  spin_ge(a.ctr, (t + 1) * 48);
  spin_ge(a.ctr + 16, (t + 1) * 48);
  // combine — hp = silu(p0+p1+bp1); ho = silu(p2+p3+p4+p5+bo1) (same order)
#pragma unroll 1
  for (int idx = blockIdx.x; idx < 1024; idx += 192) {
    const int i = idx * 256 + (int)threadIdx.x;
    const float* base = a.PD + ((size_t)(i >> 4) * 6) * 16 + (i & 15);
    const float p0 = lda_sc(base),      p1 = lda_sc(base + 16);
    const float p2 = lda_sc(base + 32), p3 = lda_sc(base + 48);
    const float p4 = lda_sc(base + 64), p5 = lda_sc(base + 80);
    float sp = (p0 + p1) + a.bp1[i & (kN1 - 1)];
    sp = sp * (1.f / (1.f + expf(-sp)));
    wr_planes(a.hph, a.hpl, i, sp);
    float so = (((p2 + p3) + p4) + p5) + a.bo1[i & (kN1 - 1)];
    so = so * (1.f / (1.f + expf(-so)));
    wr_planes(a.hoh, a.hol, i, so);
  }
}

// ====================== launch C: E GEMM + sample/loss ======================
struct ESArgs {
  const f16 *hph, *hpl, *hoh, *hol;
  const f16 *Wp2Th, *Wp2Tl, *Wo2Th, *Wo2Tl;
  float* PE;
  const float *bp2, *bo2, *unz, *acts, *Wi1, *bi1;
  float* out;
  f16 *h1h, *h1l;
  int* ctr;
  int t;
};

__global__ __launch_bounds__(256, 2) void k_e_samp(ESArgs a) {
  __shared__ ESLDS L;
  const int t = a.t;
  if (blockIdx.x < 64) {    // 64 tasks: j(4) x byp(8) x bx(2)
    const int task = permW(blockIdx.x, 4);
    const int j = task >> 4, r = task & 15, bx = r & 1, byp = r >> 1;
    const bool pr = (j < 2);
    dev_mgemm2(L.g, pr ? a.hph : a.hoh, pr ? a.hpl : a.hol, nullptr, nullptr,
               pr ? a.Wp2Th : a.Wo2Th, pr ? a.Wp2Tl : a.Wo2Tl,
               a.PE, 1024, 1024, kN1, (j & 1) * 512, 512, bx, byp, 4, j);
    flag_bump(a.ctr + bx * 16);
  }
  const int b = blockIdx.x;
  spin_ge(a.ctr + (b >> 7) * 16, (t + 1) * 32);

  // ---- softmax/unimix/KL + Gumbel argmax + h1 gather ----
  SmpLDS& S = L.s;
  const int tid = threadIdx.x;
  const float* unz_t = a.unz + (size_t)t * kB * kN1;
  __syncthreads();
#pragma unroll
  for (int c = 0; c < 4; ++c) {
    const int j = c * 256 + tid;
    const int o = b * kN1 + j;
    const float* base = a.PE + ((size_t)(o >> 4) * 4) * 16 + (o & 15);
    const float e0 = lda_sc(base),      e1 = lda_sc(base + 16);
    const float e2 = lda_sc(base + 32), e3 = lda_sc(base + 48);
    float lp = e0 + e1 + a.bp2[j];
    float lo = e2 + e3 + a.bo2[j];
    lp = fminf(fmaxf(lp, -20.f), 20.f);
    lo = fminf(fmaxf(lo, -20.f), 20.f);
    float mp = lp, mo = lo;
    for (int m = 1; m <= 16; m <<= 1) { mp = fmaxf(mp, __shfl_xor(mp, m)); mo = fmaxf(mo, __shfl_xor(mo, m)); }
    const float ep = expf(lp - mp), eo = expf(lo - mo);
    float sp = ep, so = eo;
    for (int m = 1; m <= 16; m <<= 1) { sp += __shfl_xor(sp, m); so += __shfl_xor(so, m); }
    const float pp = (ep / sp) * 0.99f + (0.01f / 32.f);
    const float po = (eo / so) * 0.99f + (0.01f / 32.f);
    float kt = po * (logf(po + 1e-8f) - logf(pp + 1e-8f));
    for (int m = 1; m <= 16; m <<= 1) kt += __shfl_xor(kt, m);
    const float u = unz_t[o];
    const float g = -logf(-logf(u + 1e-6f) + 1e-6f);
    float vv = logf(fmaxf(po, 1e-6f)) + g;
    int ii = j & 31;
    for (int m = 1; m <= 16; m <<= 1) {
      const float vo = __shfl_xor(vv, m);
      const int   io = __shfl_xor(ii, m);
      if (vo > vv || (vo == vv && io < ii)) { vv = vo; ii = io; }   // first-max ties
    }
    if ((tid & 31) == 0) { S.skl[j >> 5] = kt; S.sidx[j >> 5] = ii; }
  }
  __syncthreads();
  if (tid == 0) {
    float kl = 0.f;
    for (int gg = 0; gg < 32; ++gg) kl += S.skl[gg];
    const float dl = fmaxf(kl, 0.1f);
    a.out[(size_t)t * kB + b] = 1.0f * dl + 0.1f * dl;
  }
  if (t < kT - 1) {
    const float* act_next = a.acts + (size_t)(t + 1) * kB * kActD;
#pragma unroll
    for (int c = 0; c < 4; ++c) {
      const int j = c * 256 + tid;
      float s = a.bi1[j];
#pragma unroll
      for (int gg = 0; gg < 32; ++gg)
        s += a.Wi1[(size_t)(gg * 32 + S.sidx[gg]) * kN1 + j];
#pragma unroll
      for (int k = 0; k < kActD; ++k)
        s += act_next[b * kActD + k] * a.Wi1[(size_t)(kN1 + k) * kN1 + j];
      s = s * (1.f / (1.f + expf(-s)));
      wr_planes(a.h1h, a.h1l, (size_t)b * kN1 + j, s);
    }
  }
}

// ------------------------------------------------------------- prologue -----
struct MJob {
  const f16 *A1h, *A1l, *A2h, *A2l;
  const f16 *Wph, *Wpl;
  float* outF;
  int cols1, K, Nout, k0, klen, ny, pstride, pidx;
};
struct MJobs { MJob j[6]; };

__global__ __launch_bounds__(256, 2) void k_mgemm(MJobs js) {
  const MJob jb = js.j[blockIdx.z];
  if ((int)blockIdx.y >= jb.ny) return;
  __shared__ GemmLDS L;
  dev_mgemm(L, jb.A1h, jb.A1l, jb.A2h, jb.A2l, jb.Wph, jb.Wpl, jb.outF,
            jb.cols1, jb.K, jb.Nout, jb.k0, jb.klen, blockIdx.x, blockIdx.y,
            jb.pstride, jb.pidx);
}

__global__ __launch_bounds__(256) void k_conv(const float* src, f16* dh, f16* dl) {
  const size_t i = (size_t)blockIdx.x * 256 + threadIdx.x;
  wr_planes(dh, dl, i, src[i]);
}

__global__ __launch_bounds__(256) void k_convT(const float* src, int rowoff, int srcN,
                                               int K, f16* dh, f16* dl) {
  __shared__ float T[64][65];
  const int k0 = blockIdx.x * 64, n0 = blockIdx.y * 64;
  const int tx = threadIdx.x & 63, ty = threadIdx.x >> 6;
#pragma unroll 4
  for (int i = 0; i < 16; ++i) {
    const int k = ty * 16 + i;
    T[k][tx] = src[(size_t)(rowoff + k0 + k) * srcN + n0 + tx];
  }
  __syncthreads();
#pragma unroll 4
  for (int i = 0; i < 16; ++i) {
    const int n = ty * 16 + i;
    const float x = T[tx][n];
    const size_t o = (size_t)(n0 + n) * K + k0 + tx;
    f16 h = (f16)x;
    dh[o] = h;
    dl[o] = (f16)((x - (float)h) * kLoScale);
  }
}

__global__ __launch_bounds__(256) void k_bfused(const float* Wg, const float* bi2, float* bf) {
  const int n = blockIdx.x * 256 + threadIdx.x;
  float s = 0.f;
#pragma unroll 16
  for (int j = 0; j < 1024; ++j) s += bi2[j] * Wg[(size_t)j * kG3N + n];
  bf[n] = s;
}

__global__ __launch_bounds__(256) void k_setup(const float* b0, float* bbuf, f16* bh, f16* bl) {
  const size_t i = (size_t)blockIdx.x * 256 + threadIdx.x;
  const float b = b0[i];
  bbuf[i] = b;
  wr_planes(bh, bl, i, b);
}

__global__ void k_zero(int* p) {
  const int i = blockIdx.x * 256 + threadIdx.x;
  if (i < 512) p[i] = 0;
}

__global__ __launch_bounds__(256) void k_finish0(const float* P, const float* Wi1,
    const float* bi1, const float* act0, f16* h1h, f16* h1l) {
  const int b = blockIdx.y;
  const int j = blockIdx.x * 256 + threadIdx.x;
  __shared__ float sact[kActD];
  if (threadIdx.x < kActD) sact[threadIdx.x] = act0[b * kActD + threadIdx.x];
  __syncthreads();
  float s = P[(size_t)b * kN1 + j] + bi1[j];
#pragma unroll
  for (int k = 0; k < kActD; ++k) s += sact[k] * Wi1[(size_t)(kN1 + k) * kN1 + j];
  s = s * (1.f / (1.f + expf(-s)));
  wr_planes(h1h, h1l, (size_t)b * kN1 + j, s);
}

// ---------------------------------------------------------------------------
extern "C" void kernel_launch(void* const* d_in, const int* in_sizes, int n_in,
                              void* d_out, int out_size, void* d_ws, size_t ws_size,
                              hipStream_t stream) {
  const float* b0   = (const float*)d_in[0];
  const float* z0   = (const float*)d_in[1];
  const float* acts = (const float*)d_in[2];
  const float* obs  = (const float*)d_in[3];
  const float* unz  = (const float*)d_in[4];
  const float* Wi1  = (const float*)d_in[5];
  const float* bi1  = (const float*)d_in[6];
  const float* Wi2  = (const float*)d_in[7];
  const float* bi2  = (const float*)d_in[8];
  const float* Wg   = (const float*)d_in[9];
  const float* lns  = (const float*)d_in[10];
  const float* lnb  = (const float*)d_in[11];
  const float* Wo1  = (const float*)d_in[12];
  const float* bo1  = (const float*)d_in[13];
  const float* Wo2  = (const float*)d_in[14];
  const float* bo2  = (const float*)d_in[15];
  const float* Wp1  = (const float*)d_in[16];
  const float* bp1  = (const float*)d_in[17];
  const float* Wp2  = (const float*)d_in[18];
  const float* bp2  = (const float*)d_in[19];
  float* out = (float*)d_out;

  char* wsb = (char*)d_ws;
  size_t off = 0;
  auto allocB = [&](size_t bytes) { char* p = wsb + off; off += (bytes + 255) & ~(size_t)255; return p; };
  const size_t PL = (size_t)kB * kN1;
  const size_t S3 = (size_t)kB * kG3N;
  const size_t W1 = (size_t)kN1 * kN1;

  // region A: gate partials (4 x 256x3072 fp32 = 12 MB) — overlays Wfused_tmp
  float* Pg = (float*)allocB(4 * S3 * 4);
  float* Wfused_tmp = Pg;
  // region B: WgT planes (prologue-only) — overlays PD (6 MB) + PE (4 MB)
  f16* WgTh = (f16*)allocB(W1 * 3 * 2);
  f16* WgTl = (f16*)allocB(W1 * 3 * 2);
  float* PD = (float*)WgTh;
  float* PE = (float*)WgTl;
  // persistent planes / state
  f16* h1h = (f16*)allocB(PL * 2);  f16* h1l = (f16*)allocB(PL * 2);
  f16* bh  = (f16*)allocB(PL * 2);  f16* bl  = (f16*)allocB(PL * 2);
  f16* hph = (f16*)allocB(PL * 2);  f16* hpl = (f16*)allocB(PL * 2);
  f16* hoh = (f16*)allocB(PL * 2);  f16* hol = (f16*)allocB(PL * 2);
  f16* o0h = (f16*)allocB(PL * 2);  f16* o0l = (f16*)allocB(PL * 2);
  f16* o1h = (f16*)allocB(PL * 2);  f16* o1l = (f16*)allocB(PL * 2);
  f16* z0h = (f16*)allocB(PL * 2);  f16* z0l = (f16*)allocB(PL * 2);
  float* bbuf   = (float*)allocB(PL * 4);
  float* bfused = (float*)allocB((size_t)kG3N * 4);
  // weight planes
  f16* WfTh = (f16*)allocB(W1 * 3 * 2);  f16* WfTl = (f16*)allocB(W1 * 3 * 2);
  f16* WgBh = (f16*)allocB(W1 * 3 * 2);  f16* WgBl = (f16*)allocB(W1 * 3 * 2);
  f16* Wi2h = (f16*)allocB(W1 * 2);      f16* Wi2l = (f16*)allocB(W1 * 2);
  f16* Wi1Th = (f16*)allocB(W1 * 2);     f16* Wi1Tl = (f16*)allocB(W1 * 2);
  f16* Wo1Th = (f16*)allocB(W1 * 2 * 2); f16* Wo1Tl = (f16*)allocB(W1 * 2 * 2);
  f16* Wp1Th = (f16*)allocB(W1 * 2);     f16* Wp1Tl = (f16*)allocB(W1 * 2);
  f16* Wp2Th = (f16*)allocB(W1 * 2);     f16* Wp2Tl = (f16*)allocB(W1 * 2);
  f16* Wo2Th = (f16*)allocB(W1 * 2);     f16* Wo2Tl = (f16*)allocB(W1 * 2);
  int* cnt = (int*)allocB(4096);   // flag lines: A@0/16, B@32/48, C@64/80

  // ================= prologue =================
  k_convT<<<dim3(16, 48), 256, 0, stream>>>(Wg, 0, kG3N, 1024, WgTh, WgTl);
  k_convT<<<dim3(16, 48), 256, 0, stream>>>(Wg, 1024, kG3N, 1024, WgBh, WgBl);
  k_convT<<<dim3(16, 16), 256, 0, stream>>>(Wi1, 0, kN1, 1024, Wi1Th, Wi1Tl);
  k_convT<<<dim3(32, 16), 256, 0, stream>>>(Wo1, 0, kN1, 2048, Wo1Th, Wo1Tl);
  k_convT<<<dim3(16, 16), 256, 0, stream>>>(Wp1, 0, kN1, 1024, Wp1Th, Wp1Tl);
  k_convT<<<dim3(16, 16), 256, 0, stream>>>(Wp2, 0, kN1, 1024, Wp2Th, Wp2Tl);
  k_convT<<<dim3(16, 16), 256, 0, stream>>>(Wo2, 0, kN1, 1024, Wo2Th, Wo2Tl);
  k_conv<<<dim3(4096), 256, 0, stream>>>(Wi2, Wi2h, Wi2l);
  k_bfused<<<dim3(12), 256, 0, stream>>>(Wg, bi2, bfused);
  {  // Wfused = Wi2 @ WgTop (plain layout: pstride 1)
    MJobs J{};
    J.j[0] = { Wi2h, Wi2l, nullptr, nullptr, WgTh, WgTl, Wfused_tmp, 1024, 1024, kG3N, 0, 1024, 48, 1, 0 };
    k_mgemm<<<dim3(8, 48, 1), 256, 0, stream>>>(J);
  }
  k_convT<<<dim3(16, 48), 256, 0, stream>>>(Wfused_tmp, 0, kG3N, 1024, WfTh, WfTl);
  // WgT region dead from here -> PD/PE reuse it
  k_setup<<<dim3(1024), 256, 0, stream>>>(b0, bbuf, bh, bl);
  k_conv<<<dim3(1024), 256, 0, stream>>>(z0, z0h, z0l);
  k_conv<<<dim3(1024), 256, 0, stream>>>(obs, o0h, o0l);    // obs[0]
  k_zero<<<dim3(2), 256, 0, stream>>>(cnt);
  {  // h1(t=0): z0 @ Wi1Top -> PD (plain layout), then finisher
    MJobs J{};
    J.j[0] = { z0h, z0l, nullptr, nullptr, Wi1Th, Wi1Tl, PD, 1024, 1024, kN1, 0, 1024, 16, 1, 0 };
    k_mgemm<<<dim3(2, 16, 1), 256, 0, stream>>>(J);
  }
  k_finish0<<<dim3(4, kB), 256, 0, stream>>>(PD, Wi1, bi1, acts, h1h, h1l);

  // ================= the scan: 3 launches per step =================
  for (int t = 0; t < kT; ++t) {
    f16* oth = (t & 1) ? o1h : o0h;
    f16* otl = (t & 1) ? o1l : o0l;
    f16* onh = (t & 1) ? o0h : o1h;
    f16* onl = (t & 1) ? o0l : o1l;

    GGArgs A;
    A.h1h = h1h; A.h1l = h1l; A.bh_r = bh; A.bl_r = bl;
    A.WfTh = WfTh; A.WfTl = WfTl; A.WgBh = WgBh; A.WgBl = WgBl;
    A.Pg = Pg; A.bfused = bfused; A.lns = lns; A.lnb = lnb; A.obs = obs;
    A.bbuf = bbuf; A.bh_w = bh; A.bl_w = bl; A.onh = onh; A.onl = onl;
    A.ctr = cnt; A.t = t;
    k_gates_gru<<<dim3(256), 256, 0, stream>>>(A);

    DCArgs D;
    D.bh = bh; D.bl = bl; D.oth = oth; D.otl = otl;
    D.Wp1Th = Wp1Th; D.Wp1Tl = Wp1Tl; D.Wo1Th = Wo1Th; D.Wo1Tl = Wo1Tl;
    D.PD = PD; D.bp1 = bp1; D.bo1 = bo1;
    D.hph = hph; D.hpl = hpl; D.hoh = hoh; D.hol = hol;
    D.ctr = cnt + 32; D.t = t;
    k_d_comb<<<dim3(192), 256, 0, stream>>>(D);

    ESArgs E;
    E.hph = hph; E.hpl = hpl; E.hoh = hoh; E.hol = hol;
    E.Wp2Th = Wp2Th; E.Wp2Tl = Wp2Tl; E.Wo2Th = Wo2Th; E.Wo2Tl = Wo2Tl;
    E.PE = PE; E.bp2 = bp2; E.bo2 = bo2; E.unz = unz; E.acts = acts;
    E.Wi1 = Wi1; E.bi1 = bi1; E.out = out; E.h1h = h1h; E.h1l = h1l;
    E.ctr = cnt + 64; E.t = t;
    k_e_samp<<<dim3(256), 256, 0, stream>>>(E);
  }
}